// Round 11
// baseline (99.351 us; speedup 1.0000x reference)
//
#include <hip/hip_runtime.h>
#include <hip/hip_bf16.h>
#include <hip/hip_cooperative_groups.h>

namespace cg = cooperative_groups;

#define IN_DIM  8192
#define OUT_DIM 16384
#define BATCH   2048
#define NG      16
#define RROWS   4     // batch rows per block, packed as 4x bf16 (8 B) per index
#define TPB     512
#define NBLK    (BATCH / RROWS)        // 512
#define CPB     (OUT_DIM / NBLK)       // 32 weight-columns per block
#define NITER   (OUT_DIM / 4 / TPB)    // 8

typedef float        f32x4 __attribute__((ext_vector_type(4)));
typedef unsigned int u32x2 __attribute__((ext_vector_type(2)));
typedef unsigned int u32x4 __attribute__((ext_vector_type(4)));

// ---------------------------------------------------------------------------
// Gate mixture is linear in {a*b, a, b, 1}: out = w_ab*ab + w_a*a + w_b*b + w_c.
// ws layout (SoA): [w_ab | w_a | w_b | w_c] (4*OUT_DIM f32), then packed
// indices (OUT_DIM u32: a_idx | b_idx<<16).
// Fused cooperative kernel: each block stages its 4 rows (bf16x4-packed LDS,
// 64 KB, 2 blocks/CU) AND computes its 32 columns' weights (hidden under the
// HBM-read phase), grid.sync(), then the eval main loop. Removes the separate
// weights dispatch from the critical path.
// ---------------------------------------------------------------------------

__device__ __forceinline__ void collapse_weights(const float* __restrict__ l,
                                                 float& w_ab, float& w_a,
                                                 float& w_b, float& w_c) {
    float v[NG];
    float m = -1e30f;
#pragma unroll
    for (int k = 0; k < NG; ++k) { v[k] = l[k]; m = fmaxf(m, v[k]); }
    float s = 0.f;
#pragma unroll
    for (int k = 0; k < NG; ++k) { v[k] = __expf(v[k] - m); s += v[k]; }
    float inv = 1.0f / s;
#pragma unroll
    for (int k = 0; k < NG; ++k) v[k] *= inv;
    w_ab = v[1] - v[2] - v[4] - 2.f * v[6] - v[7] + v[8] + 2.f * v[9]
         + v[11] + v[13] - v[14];
    w_a  = v[2] + v[3] + v[6] + v[7] - v[8] - v[9] - v[12] - v[13];
    w_b  = v[4] + v[5] + v[6] + v[7] - v[8] - v[9] - v[10] - v[11];
    w_c  = v[8] + v[9] + v[10] + v[11] + v[12] + v[13] + v[14] + v[15];
}

__device__ __forceinline__ float bf16_hi_to_f(unsigned int u) {
    union { unsigned int i; float f; } c; c.i = u & 0xFFFF0000u; return c.f;
}
__device__ __forceinline__ float bf16_lo_to_f(unsigned int u) {
    union { unsigned int i; float f; } c; c.i = u << 16; return c.f;
}

__device__ __forceinline__ void eval_main_loop(
    const float* __restrict__ ws, const u32x2* rowsp,
    f32x4* __restrict__ out4, int i0) {
    const f32x4* wab4 = (const f32x4*)(ws);
    const f32x4* wa4  = (const f32x4*)(ws + OUT_DIM);
    const f32x4* wb4  = (const f32x4*)(ws + 2 * OUT_DIM);
    const f32x4* wc4  = (const f32x4*)(ws + 3 * OUT_DIM);
    const u32x4* pk4  = (const u32x4*)(ws + 4 * OUT_DIM);

    u32x4 pkb[2];
    f32x4 wabb[2], wab_[2], wbb[2], wcb[2];
    {
        int j4 = threadIdx.x;
        pkb[0]  = pk4[j4];
        wabb[0] = wab4[j4];
        wab_[0] = wa4[j4];
        wbb[0]  = wb4[j4];
        wcb[0]  = wc4[j4];
    }

    f32x4* o0 = out4 + (size_t)i0 * (OUT_DIM / 4);
    f32x4* o1 = o0 + (OUT_DIM / 4);
    f32x4* o2 = o1 + (OUT_DIM / 4);
    f32x4* o3 = o2 + (OUT_DIM / 4);

#pragma unroll
    for (int k = 0; k < NITER; ++k) {              // 8, fully unrolled
        const int cur = k & 1, nxt = cur ^ 1;
        if (k + 1 < NITER) {                       // prefetch next table
            int j4n = threadIdx.x + (k + 1) * TPB;
            pkb[nxt]  = pk4[j4n];
            wabb[nxt] = wab4[j4n];
            wab_[nxt] = wa4[j4n];
            wbb[nxt]  = wb4[j4n];
            wcb[nxt]  = wc4[j4n];
        }
        int j4 = threadIdx.x + k * TPB;
        u32x4 pk = pkb[cur];
        f32x4 wab = wabb[cur], wa = wab_[cur], wb = wbb[cur], wc = wcb[cur];
        f32x4 r0, r1, r2, r3;
#pragma unroll
        for (int c = 0; c < 4; ++c) {
            u32x2 va = rowsp[pk[c] & 0xFFFFu];
            u32x2 vb = rowsp[pk[c] >> 16];
            float a0 = bf16_lo_to_f(va.x), a1 = bf16_hi_to_f(va.x);
            float a2 = bf16_lo_to_f(va.y), a3 = bf16_hi_to_f(va.y);
            float b0 = bf16_lo_to_f(vb.x), b1 = bf16_hi_to_f(vb.x);
            float b2 = bf16_lo_to_f(vb.y), b3 = bf16_hi_to_f(vb.y);
            r0[c] = fmaf(wab[c], a0 * b0, fmaf(wa[c], a0, fmaf(wb[c], b0, wc[c])));
            r1[c] = fmaf(wab[c], a1 * b1, fmaf(wa[c], a1, fmaf(wb[c], b1, wc[c])));
            r2[c] = fmaf(wab[c], a2 * b2, fmaf(wa[c], a2, fmaf(wb[c], b2, wc[c])));
            r3[c] = fmaf(wab[c], a3 * b3, fmaf(wa[c], a3, fmaf(wb[c], b3, wc[c])));
        }
        __builtin_nontemporal_store(r0, &o0[j4]);
        __builtin_nontemporal_store(r1, &o1[j4]);
        __builtin_nontemporal_store(r2, &o2[j4]);
        __builtin_nontemporal_store(r3, &o3[j4]);
    }
}

// Fused cooperative kernel.
__global__ __launch_bounds__(TPB, 4) void fused_gate_kernel(
    const float* __restrict__ x,
    const float* __restrict__ logits,
    const int* __restrict__ a_idx,
    const int* __restrict__ b_idx,
    float* __restrict__ ws,
    f32x4* __restrict__ out4) {
    __shared__ u32x2 rowsp[IN_DIM];                // 64 KB
    const int i0 = blockIdx.x * RROWS;

    // Stage 4 rows, bf16x4-packed.
    const float* x0 = x + (size_t)i0 * IN_DIM;
#pragma unroll
    for (int t = 0; t < IN_DIM / TPB; ++t) {       // 16 iters
        int k = threadIdx.x + t * TPB;
        unsigned short b0 = __bfloat16_as_ushort(__float2bfloat16(x0[k]));
        unsigned short b1 = __bfloat16_as_ushort(__float2bfloat16(x0[k + IN_DIM]));
        unsigned short b2 = __bfloat16_as_ushort(__float2bfloat16(x0[k + 2 * IN_DIM]));
        unsigned short b3 = __bfloat16_as_ushort(__float2bfloat16(x0[k + 3 * IN_DIM]));
        u32x2 p;
        p.x = (unsigned int)b0 | ((unsigned int)b1 << 16);
        p.y = (unsigned int)b2 | ((unsigned int)b3 << 16);
        rowsp[k] = p;
    }

    // This block's share of the weight table (32 columns), hidden under the
    // grid-wide HBM-read phase.
    if (threadIdx.x < CPB) {
        int j = blockIdx.x * CPB + threadIdx.x;
        float w_ab, w_a, w_b, w_c;
        collapse_weights(logits + (size_t)j * NG, w_ab, w_a, w_b, w_c);
        ws[j]               = w_ab;
        ws[j +     OUT_DIM] = w_a;
        ws[j + 2 * OUT_DIM] = w_b;
        ws[j + 3 * OUT_DIM] = w_c;
        unsigned int* pk = (unsigned int*)(ws + 4 * OUT_DIM);
        pk[j] = (unsigned int)a_idx[j] | ((unsigned int)b_idx[j] << 16);
    }

    cg::this_grid().sync();                        // table ready, LDS staged
    eval_main_loop(ws, rowsp, out4, i0);
}

// --- two-kernel fallback path (proven round-10 structure) ------------------

__global__ __launch_bounds__(256) void gate_weights_kernel(
    const float* __restrict__ logits,
    const int* __restrict__ a_idx, const int* __restrict__ b_idx,
    float* __restrict__ ws) {
    int j = blockIdx.x * blockDim.x + threadIdx.x;
    if (j >= OUT_DIM) return;
    float w_ab, w_a, w_b, w_c;
    collapse_weights(logits + (size_t)j * NG, w_ab, w_a, w_b, w_c);
    ws[j]               = w_ab;
    ws[j +     OUT_DIM] = w_a;
    ws[j + 2 * OUT_DIM] = w_b;
    ws[j + 3 * OUT_DIM] = w_c;
    unsigned int* pk = (unsigned int*)(ws + 4 * OUT_DIM);
    pk[j] = (unsigned int)a_idx[j] | ((unsigned int)b_idx[j] << 16);
}

__global__ __launch_bounds__(TPB, 4) void gate_eval_kernel(
    const float* __restrict__ x,
    const float* __restrict__ ws,
    f32x4* __restrict__ out4) {
    __shared__ u32x2 rowsp[IN_DIM];
    const int i0 = blockIdx.x * RROWS;
    const float* x0 = x + (size_t)i0 * IN_DIM;
#pragma unroll
    for (int t = 0; t < IN_DIM / TPB; ++t) {
        int k = threadIdx.x + t * TPB;
        unsigned short b0 = __bfloat16_as_ushort(__float2bfloat16(x0[k]));
        unsigned short b1 = __bfloat16_as_ushort(__float2bfloat16(x0[k + IN_DIM]));
        unsigned short b2 = __bfloat16_as_ushort(__float2bfloat16(x0[k + 2 * IN_DIM]));
        unsigned short b3 = __bfloat16_as_ushort(__float2bfloat16(x0[k + 3 * IN_DIM]));
        u32x2 p;
        p.x = (unsigned int)b0 | ((unsigned int)b1 << 16);
        p.y = (unsigned int)b2 | ((unsigned int)b3 << 16);
        rowsp[k] = p;
    }
    __syncthreads();
    eval_main_loop(ws, rowsp, out4, i0);
}

extern "C" void kernel_launch(void* const* d_in, const int* in_sizes, int n_in,
                              void* d_out, int out_size, void* d_ws, size_t ws_size,
                              hipStream_t stream) {
    const float* x      = (const float*)d_in[0];
    const float* logits = (const float*)d_in[1];
    const int*   a_idx  = (const int*)d_in[2];
    const int*   b_idx  = (const int*)d_in[3];
    float* ws  = (float*)d_ws;                     // 320 KB SoA table
    f32x4* o4  = (f32x4*)d_out;

    void* args[6] = {(void*)&x, (void*)&logits, (void*)&a_idx,
                     (void*)&b_idx, (void*)&ws, (void*)&o4};
    hipError_t e = hipLaunchCooperativeKernel(
        (const void*)fused_gate_kernel, dim3(NBLK), dim3(TPB), args, 0, stream);
    if (e != hipSuccess) {
        // Fallback: proven two-kernel path (same math, same buffers).
        gate_weights_kernel<<<OUT_DIM / 256, 256, 0, stream>>>(
            logits, a_idx, b_idx, ws);
        gate_eval_kernel<<<NBLK, TPB, 0, stream>>>(x, ws, o4);
    }
}

// Round 12
// 40.937 us; speedup vs baseline: 2.4269x; 2.4269x over previous
//
#include <hip/hip_runtime.h>
#include <hip/hip_bf16.h>

#define IN_DIM  8192
#define OUT_DIM 16384
#define BATCH   2048
#define NG      16
#define RROWS   2     // rows per group (packed 2x bf16 per LDS word)
#define GROUPS  2     // groups per block, double-buffered LDS
#define TPB     512
#define NBLK    (BATCH / RROWS / GROUPS)   // 512
#define NITER   (OUT_DIM / 4 / TPB)        // 8

typedef float        f32x4 __attribute__((ext_vector_type(4)));
typedef unsigned int u32x4 __attribute__((ext_vector_type(4)));

// ---------------------------------------------------------------------------
// Gate mixture is linear in {a*b, a, b, 1}: out = w_ab*ab + w_a*a + w_b*b + w_c.
// ws layout (SoA): [w_ab | w_a | w_b | w_c] (4*OUT_DIM f32), then packed
// indices (OUT_DIM u32: a_idx | b_idx<<16).
// Eval: block handles 2 groups of 2 rows. Stage g0 -> eval g0 WHILE staging
// g1 (x-reads overlap out-writes) -> eval g1. bf16x2-packed LDS, 2x32 KB,
// 2 blocks/CU. One u32 gather serves 2 outputs.
// ---------------------------------------------------------------------------

__device__ __forceinline__ void collapse_weights(const float* __restrict__ l,
                                                 float& w_ab, float& w_a,
                                                 float& w_b, float& w_c) {
    float v[NG];
    float m = -1e30f;
#pragma unroll
    for (int k = 0; k < NG; ++k) { v[k] = l[k]; m = fmaxf(m, v[k]); }
    float s = 0.f;
#pragma unroll
    for (int k = 0; k < NG; ++k) { v[k] = __expf(v[k] - m); s += v[k]; }
    float inv = 1.0f / s;
#pragma unroll
    for (int k = 0; k < NG; ++k) v[k] *= inv;
    w_ab = v[1] - v[2] - v[4] - 2.f * v[6] - v[7] + v[8] + 2.f * v[9]
         + v[11] + v[13] - v[14];
    w_a  = v[2] + v[3] + v[6] + v[7] - v[8] - v[9] - v[12] - v[13];
    w_b  = v[4] + v[5] + v[6] + v[7] - v[8] - v[9] - v[10] - v[11];
    w_c  = v[8] + v[9] + v[10] + v[11] + v[12] + v[13] + v[14] + v[15];
}

// Kernel 1: per-column softmax -> SoA coefficients + packed u16 index pairs.
__global__ __launch_bounds__(256) void gate_weights_kernel(
    const float* __restrict__ logits,
    const int* __restrict__ a_idx, const int* __restrict__ b_idx,
    float* __restrict__ ws) {
    int j = blockIdx.x * blockDim.x + threadIdx.x;
    if (j >= OUT_DIM) return;
    float w_ab, w_a, w_b, w_c;
    collapse_weights(logits + (size_t)j * NG, w_ab, w_a, w_b, w_c);
    ws[j]               = w_ab;
    ws[j +     OUT_DIM] = w_a;
    ws[j + 2 * OUT_DIM] = w_b;
    ws[j + 3 * OUT_DIM] = w_c;
    unsigned int* pk = (unsigned int*)(ws + 4 * OUT_DIM);
    pk[j] = (unsigned int)a_idx[j] | ((unsigned int)b_idx[j] << 16);
}

__device__ __forceinline__ float bf16_hi_to_f(unsigned int u) {
    union { unsigned int i; float f; } c; c.i = u & 0xFFFF0000u; return c.f;
}
__device__ __forceinline__ float bf16_lo_to_f(unsigned int u) {
    union { unsigned int i; float f; } c; c.i = u << 16; return c.f;
}
__device__ __forceinline__ unsigned int pack2(float a, float b) {
    return (unsigned int)__bfloat16_as_ushort(__float2bfloat16(a))
         | ((unsigned int)__bfloat16_as_ushort(__float2bfloat16(b)) << 16);
}

// Kernel 2: grid = NBLK, TPB=512, 64 KB LDS (2 blocks/CU).
__global__ __launch_bounds__(TPB, 4) void gate_eval_kernel(
    const float* __restrict__ x,
    const float* __restrict__ ws,
    f32x4* __restrict__ out4) {
    __shared__ unsigned int buf0[IN_DIM];          // 32 KB
    __shared__ unsigned int buf1[IN_DIM];          // 32 KB
    const int b  = blockIdx.x;
    const int i0 = RROWS * b;                      // group-0 rows
    const int i1 = RROWS * b + BATCH / GROUPS;     // group-1 rows

    const f32x4* wab4 = (const f32x4*)(ws);
    const f32x4* wa4  = (const f32x4*)(ws + OUT_DIM);
    const f32x4* wb4  = (const f32x4*)(ws + 2 * OUT_DIM);
    const f32x4* wc4  = (const f32x4*)(ws + 3 * OUT_DIM);
    const u32x4* pk4  = (const u32x4*)(ws + 4 * OUT_DIM);

    u32x4 pkb[2];
    f32x4 wabb[2], wab_[2], wbb[2], wcb[2];
    {   // iter-0 table prefetch, in flight during stage-0
        int j4 = threadIdx.x;
        pkb[0]  = pk4[j4];
        wabb[0] = wab4[j4];
        wab_[0] = wa4[j4];
        wbb[0]  = wb4[j4];
        wcb[0]  = wc4[j4];
    }

    // Stage group 0.
    const float* xA = x + (size_t)i0 * IN_DIM;
#pragma unroll
    for (int t = 0; t < IN_DIM / TPB; ++t) {       // 16 iters
        int k = threadIdx.x + t * TPB;
        buf0[k] = pack2(xA[k], xA[k + IN_DIM]);
    }
    __syncthreads();

    const float* xB = x + (size_t)i1 * IN_DIM;
    f32x4* oA = out4 + (size_t)i0 * (OUT_DIM / 4);
    f32x4* oB = out4 + (size_t)i1 * (OUT_DIM / 4);

    // Eval group 0; stage group 1 inline (reads overlap writes).
#pragma unroll
    for (int k = 0; k < NITER; ++k) {              // 8, fully unrolled
        {   // two staging chunks of group 1 -> buf1
            int ka = threadIdx.x + (2 * k) * TPB;
            int kb = threadIdx.x + (2 * k + 1) * TPB;
            unsigned int va = pack2(xB[ka], xB[ka + IN_DIM]);
            unsigned int vb = pack2(xB[kb], xB[kb + IN_DIM]);
            buf1[ka] = va;
            buf1[kb] = vb;
        }
        const int cur = k & 1, nxt = cur ^ 1;
        if (k + 1 < NITER) {
            int j4n = threadIdx.x + (k + 1) * TPB;
            pkb[nxt]  = pk4[j4n];
            wabb[nxt] = wab4[j4n];
            wab_[nxt] = wa4[j4n];
            wbb[nxt]  = wb4[j4n];
            wcb[nxt]  = wc4[j4n];
        }
        int j4 = threadIdx.x + k * TPB;
        u32x4 pk = pkb[cur];
        f32x4 wab = wabb[cur], wa = wab_[cur], wb = wbb[cur], wc = wcb[cur];
        f32x4 r0, r1;
#pragma unroll
        for (int c = 0; c < 4; ++c) {
            unsigned int va = buf0[pk[c] & 0xFFFFu];
            unsigned int vb = buf0[pk[c] >> 16];
            float a0 = bf16_lo_to_f(va), a1 = bf16_hi_to_f(va);
            float b0 = bf16_lo_to_f(vb), b1 = bf16_hi_to_f(vb);
            r0[c] = fmaf(wab[c], a0 * b0, fmaf(wa[c], a0, fmaf(wb[c], b0, wc[c])));
            r1[c] = fmaf(wab[c], a1 * b1, fmaf(wa[c], a1, fmaf(wb[c], b1, wc[c])));
        }
        __builtin_nontemporal_store(r0, &oA[j4]);
        __builtin_nontemporal_store(r1, &oA[j4 + OUT_DIM / 4]);
    }

    {   // re-prefetch iter-0 table for group 1
        int j4 = threadIdx.x;
        pkb[0]  = pk4[j4];
        wabb[0] = wab4[j4];
        wab_[0] = wa4[j4];
        wbb[0]  = wb4[j4];
        wcb[0]  = wc4[j4];
    }
    __syncthreads();

    // Eval group 1.
#pragma unroll
    for (int k = 0; k < NITER; ++k) {
        const int cur = k & 1, nxt = cur ^ 1;
        if (k + 1 < NITER) {
            int j4n = threadIdx.x + (k + 1) * TPB;
            pkb[nxt]  = pk4[j4n];
            wabb[nxt] = wab4[j4n];
            wab_[nxt] = wa4[j4n];
            wbb[nxt]  = wb4[j4n];
            wcb[nxt]  = wc4[j4n];
        }
        int j4 = threadIdx.x + k * TPB;
        u32x4 pk = pkb[cur];
        f32x4 wab = wabb[cur], wa = wab_[cur], wb = wbb[cur], wc = wcb[cur];
        f32x4 r0, r1;
#pragma unroll
        for (int c = 0; c < 4; ++c) {
            unsigned int va = buf1[pk[c] & 0xFFFFu];
            unsigned int vb = buf1[pk[c] >> 16];
            float a0 = bf16_lo_to_f(va), a1 = bf16_hi_to_f(va);
            float b0 = bf16_lo_to_f(vb), b1 = bf16_hi_to_f(vb);
            r0[c] = fmaf(wab[c], a0 * b0, fmaf(wa[c], a0, fmaf(wb[c], b0, wc[c])));
            r1[c] = fmaf(wab[c], a1 * b1, fmaf(wa[c], a1, fmaf(wb[c], b1, wc[c])));
        }
        __builtin_nontemporal_store(r0, &oB[j4]);
        __builtin_nontemporal_store(r1, &oB[j4 + OUT_DIM / 4]);
    }
}

// Fallback if ws_size is too small: recompute softmax inline per column.
__global__ __launch_bounds__(256) void gate_eval_fused_kernel(
    const float* __restrict__ x,
    const float* __restrict__ logits,
    const int* __restrict__ a_idx,
    const int* __restrict__ b_idx,
    float* __restrict__ out) {
    __shared__ float row[IN_DIM];
    const int i = blockIdx.x;
    const f32x4* xr = (const f32x4*)(x + (size_t)i * IN_DIM);
    f32x4* rv = (f32x4*)row;
#pragma unroll
    for (int t = 0; t < IN_DIM / 4 / 256; ++t)
        rv[threadIdx.x + t * 256] = xr[threadIdx.x + t * 256];
    __syncthreads();
    float* o = out + (size_t)i * OUT_DIM;
    for (int k = 0; k < OUT_DIM / 256; ++k) {
        int j = threadIdx.x + k * 256;
        float w_ab, w_a, w_b, w_c;
        collapse_weights(logits + (size_t)j * NG, w_ab, w_a, w_b, w_c);
        float a = row[a_idx[j]], b = row[b_idx[j]];
        o[j] = fmaf(w_ab, a * b, fmaf(w_a, a, fmaf(w_b, b, w_c)));
    }
}

extern "C" void kernel_launch(void* const* d_in, const int* in_sizes, int n_in,
                              void* d_out, int out_size, void* d_ws, size_t ws_size,
                              hipStream_t stream) {
    const float* x      = (const float*)d_in[0];
    const float* logits = (const float*)d_in[1];
    const int*   a_idx  = (const int*)d_in[2];
    const int*   b_idx  = (const int*)d_in[3];
    float* out = (float*)d_out;

    const size_t ws_need = (size_t)(4 * OUT_DIM) * sizeof(float)
                         + (size_t)OUT_DIM * sizeof(unsigned int);  // 320 KB
    if (ws_size >= ws_need && d_ws != nullptr) {
        float* ws = (float*)d_ws;
        gate_weights_kernel<<<OUT_DIM / 256, 256, 0, stream>>>(
            logits, a_idx, b_idx, ws);
        gate_eval_kernel<<<NBLK, TPB, 0, stream>>>(x, ws, (f32x4*)out);
    } else {
        gate_eval_fused_kernel<<<BATCH, 256, 0, stream>>>(
            x, logits, a_idx, b_idx, out);
    }
}